// Round 4
// baseline (443.267 us; speedup 1.0000x reference)
//
#include <hip/hip_runtime.h>

// SkeletonConv: out[b,o,h,w] = sum_{c,k} W[o,c,k] * x[b,c, h+(k-1)*step, w+(k-1)*dil]
// B=64, C_in=C_out=16, K=3, H=W=256, fp32.
// R4: explicit MLP — batch 8 channels of loads into regs (24 independent loads
//     in flight), then 768 FMAs; boundary taps via clamped scalar loads (L1 hits)
//     instead of shfl (kills the lgkmcnt dependency). o-split x2 kept (32 acc regs).
//     R2 lesson: no min-wave launch_bounds (spilled). R3 lesson: depth-1 prefetch
//     starves MLP; need a deep batch.

constexpr int CIN = 16, COUT = 16, KK = 3, H = 256, W = 256;
constexpr int WT  = 4;            // w-elements per thread (float4)
constexpr int TPR = W / WT;       // 64 threads = one wave per (b,h,half) row
constexpr int OSPLIT = 2, OPT = COUT / OSPLIT;   // 8 output channels per thread
constexpr int CHUNK = 8;          // channels batched per load wave (MLP depth)

typedef float f4 __attribute__((ext_vector_type(4)));

__global__ __launch_bounds__(256)
void skel_conv_kernel(const float* __restrict__ x, const float* __restrict__ wgt,
                      const int* __restrict__ dil_p, const int* __restrict__ step_p,
                      float* __restrict__ out, int B)
{
    const int dil  = dil_p[0];
    const int step = step_p[0];

    const int tid  = blockIdx.x * blockDim.x + threadIdx.x;
    const int lane = tid & (TPR - 1);            // lane-in-wave; wave spans a row
    int idx = tid / TPR;                         // (b, h, half)
    const int half = idx & (OSPLIT - 1);         // both halves of a row in one block
    idx >>= 1;
    const int h = idx & (H - 1);
    const int b = idx >> 8;
    if (b >= B) return;
    const int w0    = lane * WT;
    const int obase = half * OPT;

    float acc[OPT][WT];
    #pragma unroll
    for (int o = 0; o < OPT; ++o)
        #pragma unroll
        for (int j = 0; j < WT; ++j) acc[o][j] = 0.f;

    const size_t cs = (size_t)H * W;
    const float* xr = x + (size_t)b * CIN * cs + (size_t)h * W + w0;

    if (dil == 1 && step == 0) {
        const bool l0 = (lane == 0), lN = (lane == TPR - 1);
        #pragma unroll 1
        for (int cc = 0; cc < CIN; cc += CHUNK) {
            // ---- issue phase: 24 independent loads (8 f4 + 16 scalar L1-hits) ----
            f4 v[CHUNK]; float lf[CHUNK], rt[CHUNK];
            #pragma unroll
            for (int i = 0; i < CHUNK; ++i) {
                const float* p = xr + (size_t)(cc + i) * cs;
                v[i] = *(const f4*)p;                       // coalesced, aligned
                const float lraw = p[l0 ? 0 : -1];          // clamped: in-bounds always
                const float rraw = p[lN ? 0 : WT];
                lf[i] = l0 ? 0.f : lraw;                    // zero padding at w=-1
                rt[i] = lN ? 0.f : rraw;                    // zero padding at w=256
            }
            // ---- compute phase: 8 c x 8 o x 4 w x 3 k = 768 FMAs ----
            #pragma unroll
            for (int i = 0; i < CHUNK; ++i) {
                const int c = cc + i;
                #pragma unroll
                for (int oo = 0; oo < OPT; ++oo) {
                    const float* wp = wgt + ((size_t)(obase + oo) * CIN + c) * KK;
                    const float a0 = wp[0], a1 = wp[1], a2 = wp[2];  // uniform -> s_load
                    acc[oo][0] += a0 * lf[i]   + a1 * v[i].x + a2 * v[i].y;
                    acc[oo][1] += a0 * v[i].x  + a1 * v[i].y + a2 * v[i].z;
                    acc[oo][2] += a0 * v[i].y  + a1 * v[i].z + a2 * v[i].w;
                    acc[oo][3] += a0 * v[i].z  + a1 * v[i].w + a2 * rt[i];
                }
            }
        }
    } else {
        // Generic path: clamped loads + select (never faults, any dil/step).
        #pragma unroll 1
        for (int c = 0; c < CIN; ++c) {
            const float* xc = x + (size_t)b * CIN * cs + (size_t)c * cs;
            #pragma unroll
            for (int k = 0; k < KK; ++k) {
                const int off = k - KK / 2;
                const int hh  = h + off * step;
                const bool rowok = (hh >= 0) && (hh < H);
                const int hcl = hh < 0 ? 0 : (hh > H - 1 ? H - 1 : hh);
                float t[WT];
                #pragma unroll
                for (int j = 0; j < WT; ++j) {
                    const int ww  = w0 + j + off * dil;
                    const bool ok = rowok && (ww >= 0) && (ww < W);
                    const int wcl = ww < 0 ? 0 : (ww > W - 1 ? W - 1 : ww);
                    const float vv = xc[(size_t)hcl * W + wcl];
                    t[j] = ok ? vv : 0.f;
                }
                #pragma unroll
                for (int oo = 0; oo < OPT; ++oo) {
                    const float wk = wgt[((size_t)(obase + oo) * CIN + c) * KK + k];
                    #pragma unroll
                    for (int j = 0; j < WT; ++j)
                        acc[oo][j] += wk * t[j];
                }
            }
        }
    }

    float* orow = out + ((size_t)b * COUT + obase) * cs + (size_t)h * W + w0;
    #pragma unroll
    for (int oo = 0; oo < OPT; ++oo) {
        f4 r = {acc[oo][0], acc[oo][1], acc[oo][2], acc[oo][3]};
        *(f4*)(orow + (size_t)oo * cs) = r;
    }
}

extern "C" void kernel_launch(void* const* d_in, const int* in_sizes, int n_in,
                              void* d_out, int out_size, void* d_ws, size_t ws_size,
                              hipStream_t stream) {
    const float* x    = (const float*)d_in[0];
    const float* wgt  = (const float*)d_in[1];
    const int*   dil  = (const int*)d_in[2];
    const int*   step = (const int*)d_in[3];
    float*       out  = (float*)d_out;

    const int B = in_sizes[0] / (CIN * H * W);
    const int total = B * H * OSPLIT * TPR;      // one thread per 4 w's per o-half
    const int block = 256;
    const int grid  = (total + block - 1) / block;

    skel_conv_kernel<<<grid, block, 0, stream>>>(x, wgt, dil, step, out, B);
}

// Round 5
// 365.520 us; speedup vs baseline: 1.2127x; 1.2127x over previous
//
#include <hip/hip_runtime.h>

// SkeletonConv: out[b,o,h,w] = sum_{c,k} W[o,c,k] * x[b,c, h+(k-1)*step, w+(k-1)*dil]
// B=64, C_in=C_out=16, K=3, H=W=256, fp32.
// R5: global_load_lds staging. One block per (b,h) row: DMA all 16 channel rows
//     (16KB) into LDS (16 instrs, 1KB each, linear dest), barrier, then each
//     thread computes 1 w x 16 outs (acc=16 VGPRs, taps via ds_read_b32).
//     Removes in-flight data from VGPRs entirely (R3: depth-1 starved MLP;
//     R4: reg-buffer -> 184 VGPR, 12% occ). Stage(1560cy) ~ compute(1536cy)
//     per block; ~8 resident blocks/CU overlap the phases.

constexpr int CIN = 16, COUT = 16, KK = 3, H = 256, W = 256;

__device__ __forceinline__ void load_lds16(const float* g, float* l) {
    __builtin_amdgcn_global_load_lds(
        (const __attribute__((address_space(1))) void*)g,
        (__attribute__((address_space(3))) void*)l, 16, 0, 0);
}

__global__ __launch_bounds__(256)
void skel_conv_kernel(const float* __restrict__ x, const float* __restrict__ wgt,
                      const int* __restrict__ dil_p, const int* __restrict__ step_p,
                      float* __restrict__ out, int B)
{
    const int dil  = dil_p[0];
    const int step = step_p[0];

    const int t   = threadIdx.x;       // 0..255 == w position
    const int row = blockIdx.x;        // b*256 + h
    const int h   = row & (H - 1);
    const int b   = row >> 8;
    if (b >= B) return;                // uniform per block (no barrier divergence)
    const size_t cs = (size_t)H * W;

    __shared__ float xs[CIN * W];      // 16 KB: the full (b,h) row, all channels

    float acc[COUT];
    #pragma unroll
    for (int o = 0; o < COUT; ++o) acc[o] = 0.f;

    if (dil == 1 && step == 0) {
        // ---- stage: 16 x 1KB DMA, each instr covers one channel row ----
        const int ln = t & 63, wv = t >> 6;          // lane, wave
        const float* src = x + (size_t)b * CIN * cs + (size_t)h * W + ln * 4;
        #pragma unroll
        for (int i = 0; i < CIN / 4; ++i) {          // 4 DMAs per wave
            const int c = wv * (CIN / 4) + i;
            load_lds16(src + (size_t)c * cs, &xs[c * W]);
        }
        __syncthreads();                             // vmcnt(0) + barrier

        // ---- compute: 1 w x 16 outs per thread; taps from LDS ----
        const int w  = t;
        const int wm = (w == 0)     ? 0     : w - 1; // clamped tap addresses
        const int wp = (w == W - 1) ? W - 1 : w + 1;
        #pragma unroll
        for (int c = 0; c < CIN; ++c) {
            const float* r = &xs[c * W];
            float left  = r[wm];                     // lane-contiguous -> no conflicts
            float mid   = r[w];
            float right = r[wp];
            if (w == 0)     left  = 0.f;             // zero padding
            if (w == W - 1) right = 0.f;
            #pragma unroll
            for (int o = 0; o < COUT; ++o) {
                const float* wq = wgt + ((size_t)o * CIN + c) * KK;  // uniform -> s_load
                acc[o] += wq[0] * left + wq[1] * mid + wq[2] * right;
            }
        }
    } else {
        // Generic path: clamped loads + select (never faults, any dil/step).
        #pragma unroll 1
        for (int c = 0; c < CIN; ++c) {
            const float* xc = x + (size_t)b * CIN * cs + (size_t)c * cs;
            #pragma unroll
            for (int k = 0; k < KK; ++k) {
                const int off = k - KK / 2;
                const int hh  = h + off * step;
                const int ww  = t + off * dil;
                const bool ok = (hh >= 0) && (hh < H) && (ww >= 0) && (ww < W);
                const int hcl = hh < 0 ? 0 : (hh > H - 1 ? H - 1 : hh);
                const int wcl = ww < 0 ? 0 : (ww > W - 1 ? W - 1 : ww);
                float v = xc[(size_t)hcl * W + wcl];
                v = ok ? v : 0.f;
                #pragma unroll
                for (int o = 0; o < COUT; ++o)
                    acc[o] += wgt[((size_t)o * CIN + c) * KK + k] * v;
            }
        }
    }

    // ---- store: 16 dword stores, thread-contiguous per o -> fully coalesced ----
    float* op = out + (size_t)b * COUT * cs + (size_t)h * W + t;
    #pragma unroll
    for (int o = 0; o < COUT; ++o)
        op[(size_t)o * cs] = acc[o];
}

extern "C" void kernel_launch(void* const* d_in, const int* in_sizes, int n_in,
                              void* d_out, int out_size, void* d_ws, size_t ws_size,
                              hipStream_t stream) {
    const float* x    = (const float*)d_in[0];
    const float* wgt  = (const float*)d_in[1];
    const int*   dil  = (const int*)d_in[2];
    const int*   step = (const int*)d_in[3];
    float*       out  = (float*)d_out;

    const int B = in_sizes[0] / (CIN * H * W);
    const int grid = B * H;                    // one block per (b,h) row
    skel_conv_kernel<<<grid, 256, 0, stream>>>(x, wgt, dil, step, out, B);
}

// Round 6
// 147.904 us; speedup vs baseline: 2.9970x; 2.4713x over previous
//
#include <hip/hip_runtime.h>

// SkeletonConv: out[b,o,h,w] = sum_{c,k} W[o,c,k] * x[b,c, h+(k-1)*step, w+(k-1)*dil]
// B=64, C_in=C_out=16, K=3, H=W=256, fp32.
// R6: R1 layout (64 lanes/row, 4w x 16o per thread, shfl taps) + depth-4 c-pipeline:
//     issue 4 independent f4 loads for chunk cc+1, compute chunk cc (768 FMA
//     = 1536 cy issue, covers HBM latency), ping-pong named buffers.
//     Ledger: R1 157us (no pipeline) / R2 2660 (forced spill) / R3 272 (depth-1
//     starved) / R4 477 (reg blowup 184) / R5 387 (LDS issue-bloat).

constexpr int CIN = 16, COUT = 16, KK = 3, H = 256, W = 256;
constexpr int WT  = 4;            // w-elements per thread (float4)
constexpr int TPR = W / WT;       // 64 threads = one wave per (b,h) row
constexpr int CHUNK = 4;          // c-channels per pipeline stage

typedef float f4 __attribute__((ext_vector_type(4)));

__global__ __launch_bounds__(256)
void skel_conv_kernel(const float* __restrict__ x, const float* __restrict__ wgt,
                      const int* __restrict__ dil_p, const int* __restrict__ step_p,
                      float* __restrict__ out, int B)
{
    const int dil  = dil_p[0];
    const int step = step_p[0];

    const int tid  = blockIdx.x * blockDim.x + threadIdx.x;
    const int lane = tid & (TPR - 1);            // lane-in-wave; wave spans a row
    const int idx  = tid / TPR;
    const int h    = idx & (H - 1);
    const int b    = idx >> 8;
    if (b >= B) return;
    const int w0 = lane * WT;

    float acc[COUT][WT];
    #pragma unroll
    for (int o = 0; o < COUT; ++o)
        #pragma unroll
        for (int j = 0; j < WT; ++j) acc[o][j] = 0.f;

    const size_t cs = (size_t)H * W;
    const float* xr = x + (size_t)b * CIN * cs + (size_t)h * W + w0;

    if (dil == 1 && step == 0) {
        const bool l0 = (lane == 0), lN = (lane == TPR - 1);

        auto compute_c = [&](int c, f4 v) {      // c is wave-uniform
            float left  = __shfl_up(v.w, 1);     // x[w0-1]
            float right = __shfl_down(v.x, 1);   // x[w0+4]
            if (l0) left  = 0.f;                 // zero padding
            if (lN) right = 0.f;
            #pragma unroll
            for (int o = 0; o < COUT; ++o) {
                const float* wq = wgt + ((size_t)o * CIN + c) * KK;  // uniform -> s_load
                const float a0 = wq[0], a1 = wq[1], a2 = wq[2];
                acc[o][0] += a0 * left + a1 * v.x + a2 * v.y;
                acc[o][1] += a0 * v.x  + a1 * v.y + a2 * v.z;
                acc[o][2] += a0 * v.y  + a1 * v.z + a2 * v.w;
                acc[o][3] += a0 * v.z  + a1 * v.w + a2 * right;
            }
        };

        // prologue: chunk 0 in flight
        f4 p0 = *(const f4*)(xr + 0 * cs);
        f4 p1 = *(const f4*)(xr + 1 * cs);
        f4 p2 = *(const f4*)(xr + 2 * cs);
        f4 p3 = *(const f4*)(xr + 3 * cs);

        #pragma unroll 1
        for (int cc = 0; cc < CIN / CHUNK; ++cc) {
            // issue next chunk's 4 independent loads (last iter: re-read current,
            // L1-hit, result discarded -- keeps the loop branchless)
            const int nc = (cc + 1 < CIN / CHUNK) ? (cc + 1) * CHUNK : cc * CHUNK;
            const float* nx = xr + (size_t)nc * cs;
            f4 v0 = *(const f4*)(nx + 0 * cs);
            f4 v1 = *(const f4*)(nx + 1 * cs);
            f4 v2 = *(const f4*)(nx + 2 * cs);
            f4 v3 = *(const f4*)(nx + 3 * cs);

            // compute current chunk: 4 c x 16 o x 4 w x 3 k = 768 FMA
            const int cb = cc * CHUNK;
            compute_c(cb + 0, p0);
            compute_c(cb + 1, p1);
            compute_c(cb + 2, p2);
            compute_c(cb + 3, p3);

            p0 = v0; p1 = v1; p2 = v2; p3 = v3;
        }
    } else {
        // Generic path: clamped loads + select (never faults, any dil/step).
        #pragma unroll 1
        for (int c = 0; c < CIN; ++c) {
            const float* xc = x + (size_t)b * CIN * cs + (size_t)c * cs;
            #pragma unroll
            for (int k = 0; k < KK; ++k) {
                const int off = k - KK / 2;
                const int hh  = h + off * step;
                const bool rowok = (hh >= 0) && (hh < H);
                const int hcl = hh < 0 ? 0 : (hh > H - 1 ? H - 1 : hh);
                float t[WT];
                #pragma unroll
                for (int j = 0; j < WT; ++j) {
                    const int ww  = w0 + j + off * dil;
                    const bool ok = rowok && (ww >= 0) && (ww < W);
                    const int wcl = ww < 0 ? 0 : (ww > W - 1 ? W - 1 : ww);
                    const float vv = xc[(size_t)hcl * W + wcl];
                    t[j] = ok ? vv : 0.f;
                }
                #pragma unroll
                for (int o = 0; o < COUT; ++o) {
                    const float wk = wgt[((size_t)o * CIN + c) * KK + k];
                    #pragma unroll
                    for (int j = 0; j < WT; ++j)
                        acc[o][j] += wk * t[j];
                }
            }
        }
    }

    float* orow = out + (size_t)b * COUT * cs + (size_t)h * W + w0;
    #pragma unroll
    for (int o = 0; o < COUT; ++o) {
        f4 r = {acc[o][0], acc[o][1], acc[o][2], acc[o][3]};
        *(f4*)(orow + (size_t)o * cs) = r;       // coalesced dwordx4
    }
}

extern "C" void kernel_launch(void* const* d_in, const int* in_sizes, int n_in,
                              void* d_out, int out_size, void* d_ws, size_t ws_size,
                              hipStream_t stream) {
    const float* x    = (const float*)d_in[0];
    const float* wgt  = (const float*)d_in[1];
    const int*   dil  = (const int*)d_in[2];
    const int*   step = (const int*)d_in[3];
    float*       out  = (float*)d_out;

    const int B = in_sizes[0] / (CIN * H * W);
    const int total = B * H * TPR;               // one thread per 4 output w's
    const int block = 256;
    const int grid  = (total + block - 1) / block;

    skel_conv_kernel<<<grid, block, 0, stream>>>(x, wgt, dil, step, out, B);
}

// Round 7
// 114.730 us; speedup vs baseline: 3.8636x; 1.2891x over previous
//
#include <hip/hip_runtime.h>

// SkeletonConv: out[b,o,h,w] = sum_{c,k} W[o,c,k] * x[b,c, h+(k-1)*step, w+(k-1)*dil]
// B=64, C_in=C_out=16, K=3, H=W=256, fp32.
// R7: R6 structure (64 lanes/row, 4w x 16o, shfl taps, depth-4 c-pipeline) +
//     (a) __launch_bounds__(256,4): VGPR cap 128 so the 64-float acc lives in
//         real VGPRs (R6's cap=64 forced AGPR shuttling -> 2x VALU issue),
//     (b) explicit fmaf chains: exactly 3 FMA per (o,j), no mul+add bloat.
//     Ledger: R1 157 / R2 2660 (spill) / R3 272 / R4 477 (184 VGPR) /
//             R5 387 (LDS issue-bloat) / R6 148 (VGPR=64, AGPR shuttle).

constexpr int CIN = 16, COUT = 16, KK = 3, H = 256, W = 256;
constexpr int WT  = 4;            // w-elements per thread (float4)
constexpr int TPR = W / WT;       // 64 threads = one wave per (b,h) row
constexpr int CHUNK = 4;          // c-channels per pipeline stage

typedef float f4 __attribute__((ext_vector_type(4)));

__global__ __launch_bounds__(256, 4)   // VGPR <= 128: acc(64)+pipe(16)+temps fit
void skel_conv_kernel(const float* __restrict__ x, const float* __restrict__ wgt,
                      const int* __restrict__ dil_p, const int* __restrict__ step_p,
                      float* __restrict__ out, int B)
{
    const int dil  = dil_p[0];
    const int step = step_p[0];

    const int tid  = blockIdx.x * blockDim.x + threadIdx.x;
    const int lane = tid & (TPR - 1);            // lane-in-wave; wave spans a row
    const int idx  = tid / TPR;
    const int h    = idx & (H - 1);
    const int b    = idx >> 8;
    if (b >= B) return;
    const int w0 = lane * WT;

    float acc[COUT][WT];
    #pragma unroll
    for (int o = 0; o < COUT; ++o)
        #pragma unroll
        for (int j = 0; j < WT; ++j) acc[o][j] = 0.f;

    const size_t cs = (size_t)H * W;
    const float* xr = x + (size_t)b * CIN * cs + (size_t)h * W + w0;

    if (dil == 1 && step == 0) {
        const bool l0 = (lane == 0), lN = (lane == TPR - 1);

        auto compute_c = [&](int c, f4 v) {      // c is wave-uniform
            float left  = __shfl_up(v.w, 1);     // x[w0-1]
            float right = __shfl_down(v.x, 1);   // x[w0+4]
            if (l0) left  = 0.f;                 // zero padding
            if (lN) right = 0.f;
            const float t[6] = {left, v.x, v.y, v.z, v.w, right};  // static idx only
            #pragma unroll
            for (int o = 0; o < COUT; ++o) {
                const float* wq = wgt + ((size_t)o * CIN + c) * KK;  // uniform -> s_load
                const float a0 = wq[0], a1 = wq[1], a2 = wq[2];
                #pragma unroll
                for (int j = 0; j < WT; ++j) {   // exactly 3 v_fma_f32 per (o,j)
                    acc[o][j] = fmaf(a0, t[j],     acc[o][j]);
                    acc[o][j] = fmaf(a1, t[j + 1], acc[o][j]);
                    acc[o][j] = fmaf(a2, t[j + 2], acc[o][j]);
                }
            }
        };

        // prologue: chunk 0 in flight
        f4 p0 = *(const f4*)(xr + 0 * cs);
        f4 p1 = *(const f4*)(xr + 1 * cs);
        f4 p2 = *(const f4*)(xr + 2 * cs);
        f4 p3 = *(const f4*)(xr + 3 * cs);

        #pragma unroll 1
        for (int cc = 0; cc < CIN / CHUNK; ++cc) {
            // issue next chunk's 4 independent loads (last iter: re-read current,
            // L1-hit, result discarded -- keeps the loop branchless)
            const int nc = (cc + 1 < CIN / CHUNK) ? (cc + 1) * CHUNK : cc * CHUNK;
            const float* nx = xr + (size_t)nc * cs;
            f4 v0 = *(const f4*)(nx + 0 * cs);
            f4 v1 = *(const f4*)(nx + 1 * cs);
            f4 v2 = *(const f4*)(nx + 2 * cs);
            f4 v3 = *(const f4*)(nx + 3 * cs);

            // compute current chunk: 4 c x 16 o x 4 w x 3 k = 768 FMA
            const int cb = cc * CHUNK;
            compute_c(cb + 0, p0);
            compute_c(cb + 1, p1);
            compute_c(cb + 2, p2);
            compute_c(cb + 3, p3);

            p0 = v0; p1 = v1; p2 = v2; p3 = v3;
        }
    } else {
        // Generic path: clamped loads + select (never faults, any dil/step).
        #pragma unroll 1
        for (int c = 0; c < CIN; ++c) {
            const float* xc = x + (size_t)b * CIN * cs + (size_t)c * cs;
            #pragma unroll
            for (int k = 0; k < KK; ++k) {
                const int off = k - KK / 2;
                const int hh  = h + off * step;
                const bool rowok = (hh >= 0) && (hh < H);
                const int hcl = hh < 0 ? 0 : (hh > H - 1 ? H - 1 : hh);
                float t[WT];
                #pragma unroll
                for (int j = 0; j < WT; ++j) {
                    const int ww  = w0 + j + off * dil;
                    const bool ok = rowok && (ww >= 0) && (ww < W);
                    const int wcl = ww < 0 ? 0 : (ww > W - 1 ? W - 1 : ww);
                    const float vv = xc[(size_t)hcl * W + wcl];
                    t[j] = ok ? vv : 0.f;
                }
                #pragma unroll
                for (int o = 0; o < COUT; ++o) {
                    const float wk = wgt[((size_t)o * CIN + c) * KK + k];
                    #pragma unroll
                    for (int j = 0; j < WT; ++j)
                        acc[o][j] = fmaf(wk, t[j], acc[o][j]);
                }
            }
        }
    }

    float* orow = out + (size_t)b * COUT * cs + (size_t)h * W + w0;
    #pragma unroll
    for (int o = 0; o < COUT; ++o) {
        f4 r = {acc[o][0], acc[o][1], acc[o][2], acc[o][3]};
        *(f4*)(orow + (size_t)o * cs) = r;       // coalesced dwordx4
    }
}

extern "C" void kernel_launch(void* const* d_in, const int* in_sizes, int n_in,
                              void* d_out, int out_size, void* d_ws, size_t ws_size,
                              hipStream_t stream) {
    const float* x    = (const float*)d_in[0];
    const float* wgt  = (const float*)d_in[1];
    const int*   dil  = (const int*)d_in[2];
    const int*   step = (const int*)d_in[3];
    float*       out  = (float*)d_out;

    const int B = in_sizes[0] / (CIN * H * W);
    const int total = B * H * TPR;               // one thread per 4 output w's
    const int block = 256;
    const int grid  = (total + block - 1) / block;

    skel_conv_kernel<<<grid, block, 0, stream>>>(x, wgt, dil, step, out, B);
}